// Round 3
// baseline (657.617 us; speedup 1.0000x reference)
//
#include <hip/hip_runtime.h>
#include <hip/hip_bf16.h>

// 5-layer GCN: widths 128 -> 128/64/32/16/8, N=100000 nodes, E=1600000 edges.
// R13: IN-KERNEL SOURCE-RANGE PHASING — aggr is bound by the L2-miss
//      line-fill path (335 MB @ ~2.9 TB/s; slice working set 6.4 MB/XCD >
//      4 MB L2). CSR is bucketed (src>=N/2)*N+dst (validated in R11); each
//      aggr block now processes seg0 (src half 0, 3.2 MB L2-resident) then
//      seg1, accumulating in REGISTERS (no partial round-trip — R11's
//      mistake). Uniform block work keeps co-resident blocks phase-aligned,
//      so the per-XCD instantaneous gather set is ~one half. Worst case
//      (full drift) degenerates to R10 behavior, not worse.
// R12: 8x8 register micro-tile GEMM (neutral; kept).
// R10: [f/16][N][16] aggr blocking — every fetched 64 B line fully used.
// R9:  16 KB LDS staging. R8: regular g store (L2-resident for aggr).
// R7:  aggr LDS-staged CSR indices + nt aggr output store.
// R3:  XCD-range-partitioned CSR build.

#define SCAN_B 1024
#define LDSE8  4096   // aggr8: staged edge indices (16 KB), 128 nodes/block
#define LDSE16 2048   // aggr16: staged edge indices (8 KB), 64 nodes/block

typedef float floatx4 __attribute__((ext_vector_type(4)));

// ---------------- ranged degree histogram (2-range source buckets) --------
__global__ __launch_bounds__(256) void k_count_r(const int* __restrict__ src,
                                                 const int* __restrict__ dst,
                                                 int* __restrict__ deg, int E, int N,
                                                 int half) {
    const int r  = blockIdx.x % 8;
    const int lo = (int)((long long)r * N / 8);
    const int hi = (int)((long long)(r + 1) * N / 8);
    const int nb = gridDim.x / 8;
    const int jb = blockIdx.x / 8;
    const int stride = nb * 256;
    for (int e = jb * 256 + threadIdx.x; e < E; e += stride) {
        int d = __builtin_nontemporal_load(&dst[e]);
        if (d >= lo && d < hi) {
            int s = __builtin_nontemporal_load(&src[e]);
            atomicAdd(&deg[(s >= half ? N : 0) + d], 1);
        }
    }
}

// ---------------- exclusive scan (3 kernels) ----------------
__global__ void k_scan_block(const int* __restrict__ deg, int* __restrict__ out,
                             int* __restrict__ sums, int n) {
    __shared__ int tmp[SCAN_B];
    int i = blockIdx.x * SCAN_B + threadIdx.x;
    int v = (i < n) ? deg[i] : 0;
    tmp[threadIdx.x] = v;
    __syncthreads();
    for (int off = 1; off < SCAN_B; off <<= 1) {
        int t = (threadIdx.x >= off) ? tmp[threadIdx.x - off] : 0;
        __syncthreads();
        tmp[threadIdx.x] += t;
        __syncthreads();
    }
    if (i < n) out[i] = tmp[threadIdx.x] - v;   // exclusive within block
    if (threadIdx.x == SCAN_B - 1) sums[blockIdx.x] = tmp[threadIdx.x];
}

__global__ void k_scan_sums(int* __restrict__ sums, int nb) {
    __shared__ int tmp[256];
    int v = (threadIdx.x < nb) ? sums[threadIdx.x] : 0;
    tmp[threadIdx.x] = v;
    __syncthreads();
    for (int off = 1; off < 256; off <<= 1) {
        int t = (threadIdx.x >= off) ? tmp[threadIdx.x - off] : 0;
        __syncthreads();
        tmp[threadIdx.x] += t;
        __syncthreads();
    }
    if (threadIdx.x < nb) sums[threadIdx.x] = tmp[threadIdx.x] - v;  // exclusive
}

__global__ void k_finalize(int* __restrict__ offsets, const int* __restrict__ sums,
                           const int* __restrict__ deg, int* __restrict__ cursor,
                           float* __restrict__ dinv, int n2, int n, int E) {
    int i = blockIdx.x * blockDim.x + threadIdx.x;
    if (i < n2) {
        int off = offsets[i] + sums[i / SCAN_B];
        offsets[i] = off;
        cursor[i]  = off;
    }
    if (i < n) dinv[i] = rsqrtf((float)(deg[i] + deg[n + i] + 1));  // +1 self loop
    if (i == 0) offsets[n2] = E;
}

// ---------------- ranged CSR bucket fill (2-range source buckets) ---------
__global__ __launch_bounds__(256) void k_fill_r(const int* __restrict__ src,
                                                const int* __restrict__ dst,
                                                int* __restrict__ cursor,
                                                int* __restrict__ csr_src, int E, int N,
                                                int half) {
    const int r  = blockIdx.x % 8;
    const int lo = (int)((long long)r * N / 8);
    const int hi = (int)((long long)(r + 1) * N / 8);
    const int nb = gridDim.x / 8;
    const int jb = blockIdx.x / 8;
    const int stride = nb * 256;
    for (int e = jb * 256 + threadIdx.x; e < E; e += stride) {
        int d = __builtin_nontemporal_load(&dst[e]);
        if (d >= lo && d < hi) {
            int s = __builtin_nontemporal_load(&src[e]);
            int pos = atomicAdd(&cursor[(s >= half ? N : 0) + d], 1);
            csr_src[pos] = s;
        }
    }
}

// ---------------- register-blocked GEMM (NR x NC micro-tile) ----------------
template <int FIN, int FOUT, int NR, int NC, bool BIN>
__global__ __launch_bounds__(256) void k_gemm(const float* __restrict__ x,
                                              const float* __restrict__ W,
                                              const float* __restrict__ dinv,
                                              float* __restrict__ g, int n) {
    constexpr int NFG = FOUT / NC;            // fo-groups per block
    constexpr int M   = NR * (256 / NFG);     // nodes per block
    constexpr int KC  = (FIN < 32) ? FIN : 32;
    constexpr int MP  = M + 4;
    constexpr int WP  = KC * NC + 4;          // pitch in dwords, %32 == 4
    __shared__ float Wl[NFG * WP];
    __shared__ float xt[KC * MP];

    const int tid = threadIdx.x;
    const int fg  = tid % NFG;
    const int mg  = tid / NFG;
    const int m0  = blockIdx.x * M;
    const floatx4* x4 = reinterpret_cast<const floatx4*>(x);

    float acc[NR][NC];
#pragma unroll
    for (int i = 0; i < NR; ++i)
#pragma unroll
        for (int j = 0; j < NC; ++j) acc[i][j] = 0.f;

    for (int kc0 = 0; kc0 < FIN; kc0 += KC) {
        __syncthreads();
        for (int idx = tid; idx < KC * FOUT; idx += 256) {
            int k  = idx / FOUT;
            int fo = idx % FOUT;
            Wl[(fo / NC) * WP + k * NC + (fo % NC)] = W[(kc0 + k) * FOUT + fo];
        }
        constexpr int SLOTS = KC / 4;           // float4 slots per node per chunk
        for (int s = tid; s < M * SLOTS; s += 256) {
            int ml    = s / SLOTS;
            int slot  = s % SLOTS;
            int gslot = kc0 / 4 + slot;
            int gn    = m0 + ml;
            floatx4 v = (floatx4)(0.f);
            if (gn < n) {
                size_t idx2 = BIN ? (((size_t)(gslot >> 2) * n + gn) * 4 + (gslot & 3))
                                  : ((size_t)gn * (FIN / 4) + gslot);
                v = __builtin_nontemporal_load(&x4[idx2]);
            }
            xt[(slot * 4 + 0) * MP + ml] = v.x;
            xt[(slot * 4 + 1) * MP + ml] = v.y;
            xt[(slot * 4 + 2) * MP + ml] = v.z;
            xt[(slot * 4 + 3) * MP + ml] = v.w;
        }
        __syncthreads();
#pragma unroll 4
        for (int k = 0; k < KC; ++k) {
            float xr[NR], wr[NC];
#pragma unroll
            for (int p = 0; p < NR / 4; ++p) {
                float4 v = *reinterpret_cast<const float4*>(&xt[k * MP + mg * NR + p * 4]);
                xr[p * 4 + 0] = v.x; xr[p * 4 + 1] = v.y;
                xr[p * 4 + 2] = v.z; xr[p * 4 + 3] = v.w;
            }
#pragma unroll
            for (int p = 0; p < NC / 4; ++p) {
                float4 v = *reinterpret_cast<const float4*>(&Wl[fg * WP + k * NC + p * 4]);
                wr[p * 4 + 0] = v.x; wr[p * 4 + 1] = v.y;
                wr[p * 4 + 2] = v.z; wr[p * 4 + 3] = v.w;
            }
#pragma unroll
            for (int i = 0; i < NR; ++i)
#pragma unroll
                for (int j = 0; j < NC; ++j) acc[i][j] += xr[i] * wr[j];
        }
    }

    float4* g4 = reinterpret_cast<float4*>(g);
#pragma unroll
    for (int i = 0; i < NR; ++i) {
        int gn = m0 + mg * NR + i;
        if (gn < n) {
            float d = dinv[gn];
#pragma unroll
            for (int p = 0; p < NC / 4; ++p) {
                float4 o = make_float4(acc[i][p * 4 + 0] * d, acc[i][p * 4 + 1] * d,
                                       acc[i][p * 4 + 2] * d, acc[i][p * 4 + 3] * d);
                int slot = (fg * NC) / 4 + p;
                if (FOUT >= 16)
                    g4[((size_t)(slot >> 2) * n + gn) * 4 + (slot & 3)] = o;
                else
                    g4[(size_t)gn * 2 + slot] = o;
            }
        }
    }
}

// ---------------- 16-feature-slice 2-segment CSR aggregation (layers 1-4) --
// Bucketed CSR: seg0 = src in [0,N/2), seg1 = src in [N/2,N). Each block
// processes seg0 for all its nodes, then seg1, accumulating in registers.
// Co-resident blocks stay phase-aligned (uniform work), so the per-XCD
// instantaneous gather set is ~3.2 MB (fits 4 MB L2).
__global__ __launch_bounds__(256) void k_aggr16(const float4* __restrict__ gb,
                                                const int* __restrict__ offsets,
                                                const int* __restrict__ csr_src,
                                                const float* __restrict__ dinv,
                                                const float* __restrict__ bias,
                                                float4* __restrict__ outb,
                                                int n, int nsl) {
    __shared__ int eidx[LDSE16];
    const int sl     = blockIdx.x % nsl;
    const int nb     = blockIdx.x / nsl;
    const int node0  = nb * 64;
    const int nodeHi = (node0 + 64 < n) ? node0 + 64 : n;
    const int node   = node0 + (threadIdx.x >> 2);
    const int q      = threadIdx.x & 3;

    const int eS0 = offsets[node0];
    const int eE0 = offsets[nodeHi];
    const int eS1 = offsets[n + node0];
    const int eE1 = offsets[n + nodeHi];
    const int C0  = eE0 - eS0;
    const int C1  = eE1 - eS1;
    const bool useLds = (C0 + C1 <= LDSE16);

    const bool alive = (node < n);
    int e0a = 0, e1a = 0, e0b = 0, e1b = 0;
    float dnode = 0.f;
    const float4* gs = gb + (size_t)sl * n * 4;
    float4 a0 = make_float4(0.f, 0.f, 0.f, 0.f);
    if (alive) {
        e0a = offsets[node];
        e1a = offsets[node + 1];
        e0b = offsets[n + node];
        e1b = offsets[n + node + 1];
        dnode = dinv[node];
        a0 = gs[(size_t)node * 4 + q];            // self-loop term
    }

    if (useLds) {
        for (int i = threadIdx.x; i < C0; i += 256)
            eidx[i] = __builtin_nontemporal_load(&csr_src[eS0 + i]);
        for (int i = threadIdx.x; i < C1; i += 256)
            eidx[C0 + i] = __builtin_nontemporal_load(&csr_src[eS1 + i]);
    }
    __syncthreads();
    if (!alive) return;

    float4 a1 = make_float4(0.f, 0.f, 0.f, 0.f);
    float4 a2 = a1, a3 = a1;

#pragma unroll
    for (int seg = 0; seg < 2; ++seg) {
        const int m = seg ? (e1b - e0b) : (e1a - e0a);
        const int* idx;
        if (useLds)
            idx = eidx + (seg ? (C0 + e0b - eS1) : (e0a - eS0));
        else
            idx = csr_src + (seg ? e0b : e0a);
        int i = 0;
        for (; i + 8 <= m; i += 8) {
            int s0 = idx[i + 0], s1 = idx[i + 1];
            int s2 = idx[i + 2], s3 = idx[i + 3];
            int s4 = idx[i + 4], s5 = idx[i + 5];
            int s6 = idx[i + 6], s7 = idx[i + 7];
            float4 v0 = gs[(size_t)s0 * 4 + q], v1 = gs[(size_t)s1 * 4 + q];
            float4 v2 = gs[(size_t)s2 * 4 + q], v3 = gs[(size_t)s3 * 4 + q];
            float4 v4 = gs[(size_t)s4 * 4 + q], v5 = gs[(size_t)s5 * 4 + q];
            float4 v6 = gs[(size_t)s6 * 4 + q], v7 = gs[(size_t)s7 * 4 + q];
            a0.x += v0.x; a0.y += v0.y; a0.z += v0.z; a0.w += v0.w;
            a1.x += v1.x; a1.y += v1.y; a1.z += v1.z; a1.w += v1.w;
            a2.x += v2.x; a2.y += v2.y; a2.z += v2.z; a2.w += v2.w;
            a3.x += v3.x; a3.y += v3.y; a3.z += v3.z; a3.w += v3.w;
            a0.x += v4.x; a0.y += v4.y; a0.z += v4.z; a0.w += v4.w;
            a1.x += v5.x; a1.y += v5.y; a1.z += v5.z; a1.w += v5.w;
            a2.x += v6.x; a2.y += v6.y; a2.z += v6.z; a2.w += v6.w;
            a3.x += v7.x; a3.y += v7.y; a3.z += v7.z; a3.w += v7.w;
        }
        for (; i + 4 <= m; i += 4) {
            int s0 = idx[i + 0], s1 = idx[i + 1];
            int s2 = idx[i + 2], s3 = idx[i + 3];
            float4 v0 = gs[(size_t)s0 * 4 + q], v1 = gs[(size_t)s1 * 4 + q];
            float4 v2 = gs[(size_t)s2 * 4 + q], v3 = gs[(size_t)s3 * 4 + q];
            a0.x += v0.x; a0.y += v0.y; a0.z += v0.z; a0.w += v0.w;
            a1.x += v1.x; a1.y += v1.y; a1.z += v1.z; a1.w += v1.w;
            a2.x += v2.x; a2.y += v2.y; a2.z += v2.z; a2.w += v2.w;
            a3.x += v3.x; a3.y += v3.y; a3.z += v3.z; a3.w += v3.w;
        }
        for (; i < m; ++i) {
            float4 v = gs[(size_t)idx[i] * 4 + q];
            a0.x += v.x; a0.y += v.y; a0.z += v.z; a0.w += v.w;
        }
    }
    a0.x += a1.x + a2.x + a3.x;
    a0.y += a1.y + a2.y + a3.y;
    a0.z += a1.z + a2.z + a3.z;
    a0.w += a1.w + a2.w + a3.w;

    const float* bf = bias + sl * 16 + q * 4;
    floatx4 r;
    r.x = fmaxf(dnode * a0.x + bf[0], 0.f);
    r.y = fmaxf(dnode * a0.y + bf[1], 0.f);
    r.z = fmaxf(dnode * a0.z + bf[2], 0.f);
    r.w = fmaxf(dnode * a0.w + bf[3], 0.f);
    floatx4* ob = reinterpret_cast<floatx4*>(outb);
    __builtin_nontemporal_store(r, &ob[((size_t)sl * n + node) * 4 + q]);
}

// ---------------- 8-feature CSR aggregation (layer 5, writes d_out) --------
// Source g is [N][8] = 3.2 MB (L2-resident) -> both segments, one pass.
__global__ __launch_bounds__(256) void k_aggr8(const float4* __restrict__ gb,
                                               const int* __restrict__ offsets,
                                               const int* __restrict__ csr_src,
                                               const float* __restrict__ dinv,
                                               const float* __restrict__ bias,
                                               float4* __restrict__ outb, int n) {
    __shared__ int eidx[LDSE8];
    const int node0  = blockIdx.x * 128;
    const int nodeHi = (node0 + 128 < n) ? node0 + 128 : n;
    const int node   = node0 + (threadIdx.x >> 1);
    const int h      = threadIdx.x & 1;

    const int eS0 = offsets[node0];
    const int eE0 = offsets[nodeHi];
    const int eS1 = offsets[n + node0];
    const int eE1 = offsets[n + nodeHi];
    const int C0  = eE0 - eS0;
    const int C1  = eE1 - eS1;
    const bool useLds = (C0 + C1 <= LDSE8);

    const bool alive = (node < n);
    int e0a = 0, e1a = 0, e0b = 0, e1b = 0;
    float dnode = 0.f;
    float4 a0 = make_float4(0.f, 0.f, 0.f, 0.f);
    if (alive) {
        e0a = offsets[node];
        e1a = offsets[node + 1];
        e0b = offsets[n + node];
        e1b = offsets[n + node + 1];
        dnode = dinv[node];
        a0 = gb[(size_t)node * 2 + h];            // self-loop term
    }

    if (useLds) {
        for (int i = threadIdx.x; i < C0; i += 256)
            eidx[i] = __builtin_nontemporal_load(&csr_src[eS0 + i]);
        for (int i = threadIdx.x; i < C1; i += 256)
            eidx[C0 + i] = __builtin_nontemporal_load(&csr_src[eS1 + i]);
    }
    __syncthreads();
    if (!alive) return;

    float4 a1 = make_float4(0.f, 0.f, 0.f, 0.f);
    float4 a2 = a1, a3 = a1;

#pragma unroll
    for (int seg = 0; seg < 2; ++seg) {
        const int m  = seg ? (e1b - e0b) : (e1a - e0a);
        const int* idx;
        if (useLds)
            idx = eidx + (seg ? (C0 + e0b - eS1) : (e0a - eS0));
        else
            idx = csr_src + (seg ? e0b : e0a);
        int i = 0;
        for (; i + 4 <= m; i += 4) {
            int s0 = idx[i + 0], s1 = idx[i + 1];
            int s2 = idx[i + 2], s3 = idx[i + 3];
            float4 v0 = gb[(size_t)s0 * 2 + h], v1 = gb[(size_t)s1 * 2 + h];
            float4 v2 = gb[(size_t)s2 * 2 + h], v3 = gb[(size_t)s3 * 2 + h];
            a0.x += v0.x; a0.y += v0.y; a0.z += v0.z; a0.w += v0.w;
            a1.x += v1.x; a1.y += v1.y; a1.z += v1.z; a1.w += v1.w;
            a2.x += v2.x; a2.y += v2.y; a2.z += v2.z; a2.w += v2.w;
            a3.x += v3.x; a3.y += v3.y; a3.z += v3.z; a3.w += v3.w;
        }
        for (; i < m; ++i) {
            float4 v = gb[(size_t)idx[i] * 2 + h];
            a0.x += v.x; a0.y += v.y; a0.z += v.z; a0.w += v.w;
        }
    }
    a0.x += a1.x + a2.x + a3.x;
    a0.y += a1.y + a2.y + a3.y;
    a0.z += a1.z + a2.z + a3.z;
    a0.w += a1.w + a2.w + a3.w;

    const float* bf = bias + h * 4;
    floatx4 r;
    r.x = fmaxf(dnode * a0.x + bf[0], 0.f);
    r.y = fmaxf(dnode * a0.y + bf[1], 0.f);
    r.z = fmaxf(dnode * a0.z + bf[2], 0.f);
    r.w = fmaxf(dnode * a0.w + bf[3], 0.f);
    floatx4* ob = reinterpret_cast<floatx4*>(outb);
    __builtin_nontemporal_store(r, &ob[(size_t)node * 2 + h]);
}

extern "C" void kernel_launch(void* const* d_in, const int* in_sizes, int n_in,
                              void* d_out, int out_size, void* d_ws, size_t ws_size,
                              hipStream_t stream) {
    const int N = in_sizes[0] / 128;
    const int E = in_sizes[1] / 2;
    const int half = N / 2;
    const int N2 = 2 * N;

    const float* x   = (const float*)d_in[0];
    const int*   ei  = (const int*)d_in[1];
    const int*   src = ei;
    const int*   dst = ei + E;
    const float* W1 = (const float*)d_in[2],  *b1 = (const float*)d_in[3];
    const float* W2 = (const float*)d_in[4],  *b2 = (const float*)d_in[5];
    const float* W3 = (const float*)d_in[6],  *b3 = (const float*)d_in[7];
    const float* W4 = (const float*)d_in[8],  *b4 = (const float*)d_in[9];
    const float* W5 = (const float*)d_in[10], *b5 = (const float*)d_in[11];
    float* out = (float*)d_out;

    size_t off = 0;
    auto alloc = [&](size_t bytes) {
        void* p = (char*)d_ws + off;
        off += (bytes + 255) & ~(size_t)255;
        return p;
    };
    int*   deg     = (int*)alloc((size_t)N2 * 4);
    int*   offsets = (int*)alloc((size_t)(N2 + 1) * 4);
    int*   cursor  = (int*)alloc((size_t)N2 * 4);
    int*   sums    = (int*)alloc(256 * 4);
    float* dinv    = (float*)alloc((size_t)N * 4);
    int*   csr_src = (int*)alloc((size_t)E * 4);
    float* g       = (float*)alloc((size_t)N * 128 * 4);
    float* xbuf    = (float*)alloc((size_t)N * 128 * 4);

    (void)hipMemsetAsync(deg, 0, (size_t)N2 * 4, stream);

    const int TB = 256;
    int nbs  = (N2 + SCAN_B - 1) / SCAN_B;
    int nb16 = (N + 63) / 64;        // aggr16: 64 nodes per block
    int nb8  = (N + 127) / 128;      // aggr8: 128 nodes per block
    const int RG = 2048;             // ranged kernels: 256 blocks per dst-range

    k_count_r<<<RG, TB, 0, stream>>>(src, dst, deg, E, N, half);
    k_scan_block<<<nbs, SCAN_B, 0, stream>>>(deg, offsets, sums, N2);
    k_scan_sums<<<1, 256, 0, stream>>>(sums, nbs);
    k_finalize<<<(N2 + TB - 1) / TB, TB, 0, stream>>>(offsets, sums, deg, cursor, dinv, N2, N, E);
    k_fill_r<<<RG, TB, 0, stream>>>(src, dst, cursor, csr_src, E, N, half);

    const float4* g4  = (const float4*)g;
    float4*       xb4 = (float4*)xbuf;

    // Layer 1: 128 -> 128  (8x8 tile; 8 slice16s, 2-segment in-kernel)
    k_gemm<128, 128, 8, 8, false><<<(N + 127) / 128, TB, 0, stream>>>(x, W1, dinv, g, N);
    k_aggr16<<<nb16 * 8, TB, 0, stream>>>(g4, offsets, csr_src, dinv, b1, xb4, N, 8);
    // Layer 2: 128 -> 64  (8x8 tile; 4 slice16s)
    k_gemm<128, 64, 8, 8, true><<<(N + 255) / 256, TB, 0, stream>>>(xbuf, W2, dinv, g, N);
    k_aggr16<<<nb16 * 4, TB, 0, stream>>>(g4, offsets, csr_src, dinv, b2, xb4, N, 4);
    // Layer 3: 64 -> 32  (8x4 tile; 2 slice16s)
    k_gemm<64, 32, 8, 4, true><<<(N + 255) / 256, TB, 0, stream>>>(xbuf, W3, dinv, g, N);
    k_aggr16<<<nb16 * 2, TB, 0, stream>>>(g4, offsets, csr_src, dinv, b3, xb4, N, 2);
    // Layer 4: 32 -> 16  (4x4 tile; 1 slice16)
    k_gemm<32, 16, 4, 4, true><<<(N + 255) / 256, TB, 0, stream>>>(xbuf, W4, dinv, g, N);
    k_aggr16<<<nb16 * 1, TB, 0, stream>>>(g4, offsets, csr_src, dinv, b4, xb4, N, 1);
    // Layer 5: 16 -> 8  (4x4 tile; row-major F=8; aggr8 writes d_out)
    k_gemm<16, 8, 4, 4, true><<<(N + 511) / 512, TB, 0, stream>>>(xbuf, W5, dinv, g, N);
    k_aggr8<<<nb8, TB, 0, stream>>>(g4, offsets, csr_src, dinv, b5, (float4*)out, N);
}